// Round 16
// baseline (24.249 us; speedup 1.0000x reference)
//
#include <hip/hip_runtime.h>
#include <hip/hip_fp16.h>

// Problem constants (fixed by setup_inputs):
//   x: (64,1,8,8) f32; KH=KW=5 -> oh=ow=4; rows n = b*16 + s, N = 1024
//   feat[n, i*5+j] = x[b*64 + (oy+i)*8 + (ox+j)], s = oy*4+ox
//   idx0:(128,36,6) in [0,25), lut0:(128,36,64)
//   idx1:(128, 6,6) in [0,36), lut1:(128, 6,64)
//   idx2:(128, 1,6) in [0, 6), lut2:(128, 1,64)
//   out[b,t,oy,ox] = b*2048 + t*16 + s
#define T_TREES 128
#define M0 36
#define M1 6
#define NNODES 43
#define XPAD 67   // odd LDS image stride -> gather banks sweep residues (~2-way, free)
#define SLUT_ELEMS (T_TREES * NNODES * 64)   // 1.41 MB

typedef float v2f __attribute__((ext_vector_type(2)));

__device__ __forceinline__ float sigmoidf(float v) {
    return 1.f / (1.f + __expf(-v));
}

// ---------------- pre-pass: slut[t][node][64] = sigmoid(lut) ----------------
// Done once per tree (not 8x per eighth-block) so the main kernel can hoist P
// from global/L2 at a wave-uniform address -- off the LDS pipe, which R15's
// arithmetic shows was the binding pipe (~7us of broadcast ds_read_b128).
__global__ __launch_bounds__(256) void sig_kernel(
    const float* __restrict__ lut0, const float* __restrict__ lut1,
    const float* __restrict__ lut2, float* __restrict__ slut) {
    int i4 = blockIdx.x * 256 + threadIdx.x;   // 88064 float4s, 344 blocks exact
    int j4 = i4 & 15;
    int tn = i4 >> 4;          // t*43 + node
    int t = tn / NNODES;
    int node = tn - t * NNODES;
    const float4* src;
    if (node < M0)            src = (const float4*)lut0 + (t * M0 + node) * 16 + j4;
    else if (node < M0 + M1)  src = (const float4*)lut1 + (t * M1 + (node - M0)) * 16 + j4;
    else                      src = (const float4*)lut2 + t * 16 + j4;
    float4 v = *src;
    float4 r;
    r.x = sigmoidf(v.x); r.y = sigmoidf(v.y);
    r.z = sigmoidf(v.z); r.w = sigmoidf(v.w);
    reinterpret_cast<float4*>(slut)[i4] = r;
}

// Pair-weight, FMA-lean: {(1-a)(1-b),(1-a)b,a(1-b),ab} per 2-row lane.
__device__ __forceinline__ void pair_w(v2f a, v2f b, v2f w[4]) {
    v2f ab = a * b;
    w[3] = ab;
    w[2] = a - ab;
    w[1] = b - ab;
    w[0] = (1.f - a) - w[1];
}

// Trilinear contraction over a row-pair; P compile-time indexed (VGPR/SGPR).
__device__ __forceinline__ v2f lut_node_v2(const float* __restrict__ P,
                                           v2f a, v2f b, v2f c,
                                           v2f d, v2f e, v2f f) {
    v2f wa[4], wb[4], wc[4];
    pair_w(a, b, wa);
    pair_w(c, d, wb);
    pair_w(e, f, wc);
    v2f acc = {0.f, 0.f};
#pragma unroll
    for (int p = 0; p < 4; ++p) {
        v2f tp = {0.f, 0.f};
#pragma unroll
        for (int q = 0; q < 4; ++q) {
            const float* Pq = P + p * 16 + q * 4;
            v2f tq = Pq[0] * wc[0] + Pq[1] * wc[1] + Pq[2] * wc[2] + Pq[3] * wc[3];
            tp += tq * wb[q];
        }
        acc += tp * wa[p];
    }
    return acc;
}

// batch-hoist one node's 64 sigmoided LUT values from global (wave-uniform
// address -> scalar/L2 path; ONE wait then load-free FMA stream. This is the
// R4 batching mechanism with the source moved off the LDS pipe.)
__device__ __forceinline__ void hoist_P(const float* __restrict__ src, float P[64]) {
#pragma unroll
    for (int i = 0; i < 16; ++i) {
        float4 v = reinterpret_cast<const float4*>(src)[i];
        P[4 * i] = v.x; P[4 * i + 1] = v.y; P[4 * i + 2] = v.z; P[4 * i + 3] = v.w;
    }
}

// ===== fused 3-layer kernel: block = (tree t, 128-row eighth), 256 thr =====
// LDS ~9.8 KB (no Ps staging, f16 h0); (256,4) caps VGPR at 128 (live set
// ~100: P 64 + gathers 12 + misc) -> 4 blocks/CU x 4 waves = 4 waves/SIMD,
// double R15's residency, covering the per-node P-load latency via TLP.
__global__ __launch_bounds__(256, 4) void fused_kernel(
    const float* __restrict__ x,
    const int* __restrict__ idx0, const int* __restrict__ idx1,
    const int* __restrict__ idx2, const float* __restrict__ slut,
    float* __restrict__ out) {
    __shared__ float xs[8 * XPAD];                // 2144 B: eighth's 8 images
    __shared__ __half2 h0s[M0 * 64];              // 4608 B (pair-packed f16)
    __shared__ __align__(8) float h1s[M1 * 128];  // 3072 B  => 9824 B total

    const int tid = threadIdx.x;
    const int bx = blockIdx.x;            // bx = e*128 + t (t fast -> XCD locality)
    const int t = bx & 127;
    const int e = bx >> 7;                // row eighth [0,8)

    // ---- prologue: stage this eighth's 8 images (512 floats) ----
    const float* __restrict__ xq = x + e * 512;
    for (int i = tid; i < 512; i += 256)
        xs[(i >> 6) * XPAD + (i & 63)] = xq[i];
    __syncthreads();

    const int w = __builtin_amdgcn_readfirstlane(tid >> 6);  // uniform wave id
    const int ln = tid & 63;
    const float* __restrict__ slt = slut + t * (NNODES * 64);

    // ---- layer 0: wave w -> nodes 9w..9w+8, one 64-pair iter each ----
#pragma unroll 1
    for (int k = 0; k < 9; ++k) {
        const int m = w * 9 + k;
        float P[64];
        hoist_P(slt + m * 64, P);
        const int* id = idx0 + (t * M0 + m) * 6;   // wave-uniform -> scalar
        int di[6];
#pragma unroll
        for (int j = 0; j < 6; ++j) {
            int kk = id[j];
            int ii = (kk * 13) >> 6;      // kk/5 for kk in [0,25)
            di[j] = kk - 5 * ii + ii * 8; // i*8 + j window offset
        }
        // pair p = ln: rows 2p,2p+1 of this eighth
        int b = ln >> 3;                  // local image [0,8)
        int s = (ln & 7) * 2;             // even position
        int xb = b * XPAD + (s >> 2) * 8 + (s & 3);
        v2f g[6];
#pragma unroll
        for (int j = 0; j < 6; ++j) {
            int a0 = xb + di[j];
            g[j].x = xs[a0];              // fuses -> ds_read2_b32
            g[j].y = xs[a0 + 1];
        }
        v2f r = lut_node_v2(P, g[0], g[1], g[2], g[3], g[4], g[5]);
        h0s[m * 64 + ln] = __floats2half2_rn(r.x, r.y);
    }
    __syncthreads();

    // ---- layer 1: wave0: nodes 0,4; wave1: 1,5; wave2: 2; wave3: 3 ----
#pragma unroll 1
    for (int m1 = w; m1 < M1; m1 += 4) {
        float P[64];
        hoist_P(slt + (M0 + m1) * 64, P);
        const int* id = idx1 + (t * M1 + m1) * 6;
        v2f g[6];
#pragma unroll
        for (int j = 0; j < 6; ++j) {
            float2 f = __half22float2(h0s[id[j] * 64 + ln]);
            g[j].x = f.x; g[j].y = f.y;
        }
        v2f r = lut_node_v2(P, g[0], g[1], g[2], g[3], g[4], g[5]);
        *reinterpret_cast<v2f*>(h1s + m1 * 128 + 2 * ln) = r;
    }
    __syncthreads();

    // ---- layer 2: wave 0, one pair per lane ----
    if (tid < 64) {
        float P[64];
        hoist_P(slt + (M0 + M1) * 64, P);
        const int* id = idx2 + t * 6;
        int rl = 2 * tid;                 // local even row
        v2f g[6];
#pragma unroll
        for (int j = 0; j < 6; ++j)
            g[j] = *reinterpret_cast<const v2f*>(h1s + id[j] * 128 + rl);
        v2f o = lut_node_v2(P, g[0], g[1], g[2], g[3], g[4], g[5]);
        int row = e * 128 + rl;
        int b = row >> 4, s = row & 15;
        *reinterpret_cast<v2f*>(out + b * (T_TREES * 16) + t * 16 + s) = o;
    }
}

// ===== fallback (ws too small): R15-style self-contained kernel =====
__global__ __launch_bounds__(256, 2) void fused_fb_kernel(
    const float* __restrict__ x,
    const int* __restrict__ idx0, const float* __restrict__ lut0,
    const int* __restrict__ idx1, const float* __restrict__ lut1,
    const int* __restrict__ idx2, const float* __restrict__ lut2,
    float* __restrict__ out) {
    __shared__ float xs[16 * XPAD];
    __shared__ __align__(16) float Ps[NNODES * 64];
    __shared__ __half2 h0s[M0 * 128];
    __shared__ __align__(8) float h1s[M1 * 256];

    const int tid = threadIdx.x;
    const int bx = blockIdx.x;
    const int t = bx & 127;
    const int q = bx >> 7;

    const float* __restrict__ xq = x + q * 1024;
    for (int i = tid; i < 1024; i += 256)
        xs[(i >> 6) * XPAD + (i & 63)] = xq[i];
    for (int i = tid; i < NNODES * 64; i += 256) {
        float v;
        if (i < M0 * 64)              v = lut0[t * (M0 * 64) + i];
        else if (i < (M0 + M1) * 64)  v = lut1[t * (M1 * 64) + (i - M0 * 64)];
        else                          v = lut2[t * 64 + (i - (M0 + M1) * 64)];
        Ps[i] = sigmoidf(v);
    }
    __syncthreads();

    const int w = tid >> 6, ln = tid & 63;
#pragma unroll 1
    for (int k = 0; k < 9; ++k) {
        const int m = w * 9 + k;
        float P[64];
        hoist_P(Ps + m * 64, P);
        const int* id = idx0 + (t * M0 + m) * 6;
        int di[6];
#pragma unroll
        for (int j = 0; j < 6; ++j) {
            int kk = id[j];
            int ii = (kk * 13) >> 6;
            di[j] = kk - 5 * ii + ii * 8;
        }
#pragma unroll
        for (int u = 0; u < 2; ++u) {
            int p = u * 64 + ln;
            int b = p >> 3;
            int s = (p & 7) * 2;
            int xb = b * XPAD + (s >> 2) * 8 + (s & 3);
            v2f g[6];
#pragma unroll
            for (int j = 0; j < 6; ++j) {
                int a0 = xb + di[j];
                g[j].x = xs[a0];
                g[j].y = xs[a0 + 1];
            }
            v2f r = lut_node_v2(P, g[0], g[1], g[2], g[3], g[4], g[5]);
            h0s[m * 128 + p] = __floats2half2_rn(r.x, r.y);
        }
    }
    __syncthreads();
#pragma unroll 1
    for (int m1 = w; m1 < M1; m1 += 4) {
        float P[64];
        hoist_P(Ps + (M0 + m1) * 64, P);
        const int* id = idx1 + (t * M1 + m1) * 6;
#pragma unroll
        for (int u = 0; u < 2; ++u) {
            int p = u * 64 + ln;
            v2f g[6];
#pragma unroll
            for (int j = 0; j < 6; ++j) {
                float2 f = __half22float2(h0s[id[j] * 128 + p]);
                g[j].x = f.x; g[j].y = f.y;
            }
            v2f r = lut_node_v2(P, g[0], g[1], g[2], g[3], g[4], g[5]);
            *reinterpret_cast<v2f*>(h1s + m1 * 256 + 2 * p) = r;
        }
    }
    __syncthreads();
    if (tid < 128) {
        float P[64];
        hoist_P(Ps + (M0 + M1) * 64, P);
        const int* id = idx2 + t * 6;
        int rl = 2 * tid;
        v2f g[6];
#pragma unroll
        for (int j = 0; j < 6; ++j)
            g[j] = *reinterpret_cast<const v2f*>(h1s + id[j] * 256 + rl);
        v2f o = lut_node_v2(P, g[0], g[1], g[2], g[3], g[4], g[5]);
        int row = q * 256 + rl;
        int b = row >> 4, s = row & 15;
        *reinterpret_cast<v2f*>(out + b * (T_TREES * 16) + t * 16 + s) = o;
    }
}

extern "C" void kernel_launch(void* const* d_in, const int* in_sizes, int n_in,
                              void* d_out, int out_size, void* d_ws, size_t ws_size,
                              hipStream_t stream) {
    const float* x    = (const float*)d_in[0];
    const int*   idx0 = (const int*)  d_in[1];
    const float* lut0 = (const float*)d_in[2];
    const int*   idx1 = (const int*)  d_in[3];
    const float* lut1 = (const float*)d_in[4];
    const int*   idx2 = (const int*)  d_in[5];
    const float* lut2 = (const float*)d_in[6];
    float* out = (float*)d_out;

    if (ws_size >= (size_t)SLUT_ELEMS * sizeof(float)) {   // 1.41 MB
        float* slut = (float*)d_ws;
        sig_kernel<<<SLUT_ELEMS / 4 / 256, 256, 0, stream>>>(lut0, lut1, lut2, slut); // 344 blocks
        fused_kernel<<<dim3(8 * T_TREES), 256, 0, stream>>>(
            x, idx0, idx1, idx2, slut, out);               // 1024 blocks = 4/CU
    } else {
        fused_fb_kernel<<<dim3(4 * T_TREES), 256, 0, stream>>>(
            x, idx0, lut0, idx1, lut1, idx2, lut2, out);
    }
}